// Round 10
// baseline (113.190 us; speedup 1.0000x reference)
//
#include <hip/hip_runtime.h>
#include <hip/hip_bf16.h>

// Problem constants
#define NB    4096          // batch
#define ND    256           // dim
#define NP    2             // positives per anchor
#define TOT   (NB * 3)      // 12288 rows: [a | p0 | p1]
#define RB    256           // row bytes in F (fp8: 1 B/elem)
#define NCHUNK 48           // 3 parts x 16 chunks; each chunk within one part
#define COLS_PER_CHUNK 256
#define TILES 16
#define NEG_INIT (-4.0f)

typedef float f32x4 __attribute__((ext_vector_type(4)));
typedef long  longx2 __attribute__((ext_vector_type(2)));

// ws layout (bytes)
#define WS_F_OFF    0                            // uchar[12288*256] fp8 normalized
#define WS_POS_OFF  (TOT * RB)                   // float[4096*2] pos distances
#define WS_PART_OFF (WS_POS_OFF + NB * NP * 4)   // float[3][4096][16] partial maxima

// Kernel 1: normalize rows of [a | p0 | p1] -> fp8 e4m3 matrix F; p-rows also
// emit the exact fp32 positive distance. One wave per row.
__global__ void norm_pos_kernel(const float* __restrict__ anchor,
                                const float* __restrict__ positive,
                                unsigned char* __restrict__ F,
                                float* __restrict__ posArr) {
    int wid = threadIdx.x >> 6, lane = threadIdx.x & 63;
    int row = blockIdx.x * 4 + wid;              // grid = 3072
    if (row < NB) {
        const float* src = anchor + (size_t)row * ND;
        float4 x = *(const float4*)(src + lane * 4);
        float ss = x.x * x.x + x.y * x.y + x.z * x.z + x.w * x.w;
        #pragma unroll
        for (int m = 1; m < 64; m <<= 1) ss += __shfl_xor(ss, m, 64);
        float inv = 1.0f / fmaxf(sqrtf(ss), 1e-12f);
        int pk = __builtin_amdgcn_cvt_pk_fp8_f32(x.x * inv, x.y * inv, 0, false);
        pk = __builtin_amdgcn_cvt_pk_fp8_f32(x.z * inv, x.w * inv, pk, true);
        *(int*)(F + (size_t)row * RB + lane * 4) = pk;
    } else {
        int q = row - NB;
        int v = q >> 12;                         // 0 or 1
        int j = q & (NB - 1);
        const float* sp = positive + (size_t)(j * NP + v) * ND;
        const float* sa = anchor + (size_t)j * ND;
        float4 xp = *(const float4*)(sp + lane * 4);
        float4 xa = *(const float4*)(sa + lane * 4);
        float sspv = xp.x * xp.x + xp.y * xp.y + xp.z * xp.z + xp.w * xp.w;
        float ssa  = xa.x * xa.x + xa.y * xa.y + xa.z * xa.z + xa.w * xa.w;
        float dot  = xa.x * xp.x + xa.y * xp.y + xa.z * xp.z + xa.w * xp.w;
        #pragma unroll
        for (int m = 1; m < 64; m <<= 1) {
            sspv += __shfl_xor(sspv, m, 64);
            ssa  += __shfl_xor(ssa, m, 64);
            dot  += __shfl_xor(dot, m, 64);
        }
        float invp = 1.0f / fmaxf(sqrtf(sspv), 1e-12f);
        int pk = __builtin_amdgcn_cvt_pk_fp8_f32(xp.x * invp, xp.y * invp, 0, false);
        pk = __builtin_amdgcn_cvt_pk_fp8_f32(xp.z * invp, xp.w * invp, pk, true);
        *(int*)(F + (size_t)row * RB + lane * 4) = pk;
        if (lane == 0) {
            float inva = 1.0f / fmaxf(sqrtf(ssa), 1e-12f);
            float dn = dot * inva * invp;
            float sq = 2.0f - 2.0f * dn;
            posArr[j * NP + v] = sqrtf(fmaxf(sq, 1e-12f));
        }
    }
}

// Kernel 2: fused masked-max Gram, FP8, two-phase LDS (32 KB), register-
// batched staging. Each phase stages 8 tiles (128 cols): every thread first
// loads its entire 128 B slice into 16 long regs (ONE global round-trip),
// then does all ds_writes. Phase-1 loads are issued before phase-0 compute,
// hiding their latency under 8 tiles of MFMA. 33 KB LDS -> 3 blocks/CU.
__global__ __launch_bounds__(256, 3) void gram_max_kernel(
        const unsigned char* __restrict__ F,
        const int* __restrict__ labels,
        float* __restrict__ partials) {
    __shared__ unsigned char ldsB[8 * 4096];      // 32 KB: 8 tile slots
    __shared__ int slab[COLS_PER_CHUNK];          // 1 KB column labels
    int tid = threadIdx.x;
    int wid = tid >> 6, lane = tid & 63;
    int l15 = lane & 15, quad = lane >> 4;

    int id = blockIdx.x;                         // 0..767
    int chunk = id >> 4;                         // 0..47
    int rbi   = id & 15;                         // 0..15 row-block index

    int rowBase = rbi * 256 + wid * 64;
    int col0 = chunk * COLS_PER_CHUNK;
    int part = chunk >> 4;                       // 0=aa, 1=p0, 2=p1
    const unsigned char* Fb = F;

    // Staging map: thread owns column cp = tid&127 of the current phase and
    // K-half h = tid>>7 (kk in [h*4, h*4+4)). 128 B per thread per phase.
    int cp = tid & 127, h = tid >> 7;
    int kkb = h * 4;
    int slot = cp >> 4;                          // tile slot (same both phases)
    int c15 = cp & 15;

    long bt[4][4];                               // 32 VGPRs staging batch
    auto stage_load = [&](int phase) {
        const unsigned char* g = Fb + (size_t)(col0 + phase * 128 + cp) * RB + kkb * 32;
        #pragma unroll
        for (int j = 0; j < 4; ++j) {
            longx2 u = *(const longx2*)(g + j * 32);
            longx2 v = *(const longx2*)(g + j * 32 + 16);
            bt[j][0] = u.x; bt[j][1] = u.y; bt[j][2] = v.x; bt[j][3] = v.y;
        }
    };
    auto stage_write = [&]() {
        unsigned char* d = ldsB + slot * 4096 + kkb * 512 + c15 * 8;
        #pragma unroll
        for (int j = 0; j < 4; ++j)
            #pragma unroll
            for (int q = 0; q < 4; ++q)
                *(long*)(d + j * 512 + q * 128) = bt[j][q];
    };

    slab[tid] = labels[(col0 & (NB - 1)) + tid];
    stage_load(0);
    stage_write();

    // A preload: af[s][kk] = 8 fp8 K-bytes, row rowBase+s*16+l15, K-offset
    // quad*8 + kk*32 (verified fp8 16x16x32 A layout, R8).
    long af[4][8];
    #pragma unroll
    for (int s = 0; s < 4; ++s) {
        const unsigned char* ar = Fb + (size_t)(rowBase + s * 16 + l15) * RB + quad * 8;
        #pragma unroll
        for (int kk = 0; kk < 8; ++kk)
            af[s][kk] = *(const long*)(ar + kk * 32);
    }
    // Row labels, byte-packed (labels < 200 fit a byte).
    unsigned rlp[4];
    #pragma unroll
    for (int s = 0; s < 4; ++s) {
        const int* lb = labels + rowBase + s * 16 + quad * 4;
        rlp[s] = (unsigned)lb[0] | ((unsigned)lb[1] << 8)
               | ((unsigned)lb[2] << 16) | ((unsigned)lb[3] << 24);
    }

    float vmax[4][4];
    #pragma unroll
    for (int s = 0; s < 4; ++s)
        #pragma unroll
        for (int r = 0; r < 4; ++r) vmax[s][r] = NEG_INIT;

    __syncthreads();                 // phase-0 data visible
    stage_load(1);                   // phase-1 loads in flight under compute

    #pragma unroll
    for (int phase = 0; phase < 2; ++phase) {
        int ctBase = phase * 8;
        for (int t = 0; t < 8; ++t) {
            int ct = ctBase + t;
            long bfr[8];
            #pragma unroll
            for (int kk = 0; kk < 8; ++kk)
                bfr[kk] = *(const long*)&ldsB[t * 4096 + kk * 512 + lane * 8];

            int lc = slab[ct * 16 + l15];
            unsigned lcq = (unsigned)lc * 0x01010101u;

            f32x4 acc[4];
            #pragma unroll
            for (int s = 0; s < 4; ++s) acc[s] = (f32x4){0.f, 0.f, 0.f, 0.f};
            #pragma unroll
            for (int kk = 0; kk < 8; ++kk)
                #pragma unroll
                for (int s = 0; s < 4; ++s)
                    acc[s] = __builtin_amdgcn_mfma_f32_16x16x32_fp8_fp8(af[s][kk], bfr[kk], acc[s], 0, 0, 0);

            #pragma unroll
            for (int s = 0; s < 4; ++s) {
                unsigned x = rlp[s] ^ lcq;     // byte r == 0 iff labels equal
                #pragma unroll
                for (int r = 0; r < 4; ++r) {
                    bool neq = ((x >> (8 * r)) & 0xffu) != 0u;
                    vmax[s][r] = fmaxf(vmax[s][r], neq ? acc[s][r] : NEG_INIT);
                }
            }
        }
        if (phase == 0) {
            __syncthreads();         // phase-0 reads done
            stage_write();           // loads arrived during the 8 tiles above
            __syncthreads();         // phase-1 data visible
        }
    }

    // Reduce max across the 16 column-lanes (same quad = same rows)
    #pragma unroll
    for (int m = 1; m < 16; m <<= 1)
        #pragma unroll
        for (int s = 0; s < 4; ++s)
            #pragma unroll
            for (int r = 0; r < 4; ++r)
                vmax[s][r] = fmaxf(vmax[s][r], __shfl_xor(vmax[s][r], m, 64));

    if (l15 == 0) {
        #pragma unroll
        for (int s = 0; s < 4; ++s)
            #pragma unroll
            for (int r = 0; r < 4; ++r) {
                int row = rowBase + s * 16 + quad * 4 + r;
                partials[(size_t)part * NB * 16 + (size_t)row * 16 + (chunk & 15)] = vmax[s][r];
            }
    }
}

// Kernel 3: combine per-part chunk partials -> neg distances -> hinge -> mean.
__global__ void finalize_kernel(const float* __restrict__ partials,
                                const float* __restrict__ posArr,
                                float* __restrict__ out) {
    int row = blockIdx.x * 256 + threadIdx.x;    // grid = 16 -> 4096 rows
    const float* pa = partials + (size_t)row * 16;
    const float* pb = pa + (size_t)NB * 16;
    const float* pc = pb + (size_t)NB * 16;
    float ma = NEG_INIT, m0 = NEG_INIT, m1 = NEG_INIT;
    #pragma unroll
    for (int j = 0; j < 16; ++j) {
        ma = fmaxf(ma, pa[j]);
        m0 = fmaxf(m0, pb[j]);
        m1 = fmaxf(m1, pc[j]);
    }
    float n0 = sqrtf(fmaxf(2.0f - 2.0f * fmaxf(ma, m0), 1e-12f));
    float n1 = sqrtf(fmaxf(2.0f - 2.0f * fmaxf(ma, m1), 1e-12f));
    float l = fmaxf(posArr[row * 2 + 0] - n0 + 1.0f, 0.0f)
            + fmaxf(posArr[row * 2 + 1] - n1 + 1.0f, 0.0f);
    int lane = threadIdx.x & 63, wid = threadIdx.x >> 6;
    #pragma unroll
    for (int m = 1; m < 64; m <<= 1) l += __shfl_xor(l, m, 64);
    __shared__ float wsum[4];
    if (lane == 0) wsum[wid] = l;
    __syncthreads();
    if (threadIdx.x == 0) {
        float s = wsum[0] + wsum[1] + wsum[2] + wsum[3];
        atomicAdd(out, s * (1.0f / (NB * NP)));
    }
}

extern "C" void kernel_launch(void* const* d_in, const int* in_sizes, int n_in,
                              void* d_out, int out_size, void* d_ws, size_t ws_size,
                              hipStream_t stream) {
    const float* anchor   = (const float*)d_in[0];
    const float* positive = (const float*)d_in[1];
    const int*   labels   = (const int*)d_in[2];
    float* out = (float*)d_out;

    unsigned char* F = (unsigned char*)((char*)d_ws + WS_F_OFF);
    float* posArr    = (float*)((char*)d_ws + WS_POS_OFF);
    float* partials  = (float*)((char*)d_ws + WS_PART_OFF);

    norm_pos_kernel<<<TOT / 4, 256, 0, stream>>>(anchor, positive, F, posArr);
    gram_max_kernel<<<(NB / 256) * NCHUNK, 256, 0, stream>>>(F, labels, partials);
    hipMemsetAsync(d_out, 0, sizeof(float), stream);
    finalize_kernel<<<NB / 256, 256, 0, stream>>>(partials, posArr, out);
}

// Round 11
// 93.566 us; speedup vs baseline: 1.2097x; 1.2097x over previous
//
#include <hip/hip_runtime.h>
#include <hip/hip_bf16.h>

// Problem constants
#define NB    4096          // batch
#define ND    256           // dim
#define NP    2             // positives per anchor
#define TOT   (NB * 3)      // 12288 rows: [a | p0 | p1]
#define NCHUNK 48           // 3 parts x 16 chunks; each chunk within one part
#define COLS_PER_CHUNK 256
#define TILES 16
#define NEG_INIT (-4.0f)

// F2 is stored FRAGMENT-MAJOR: for 16-row group g, K-block kk (32 fp8), the
// 512-byte block F2[g*4096 + kk*512 + (quad*16 + r15)*8 + j] holds byte
// k = kk*32 + quad*8 + j of row g*16 + r15. A wave's MFMA fragment load is
// then lane-contiguous (lane*8): ONE 512-B coalesced load = 8 cache lines,
// vs 64 lines for the old row-major gather. This attacks the TA request-rate
// bottleneck that R1-R10 isolated (byte-halving gave only 1.14x; swizzles,
// barriers, occupancy all neutral -> requests, not bytes, were binding).
typedef float f32x4 __attribute__((ext_vector_type(4)));

// ws layout (bytes)
#define WS_F_OFF    0                            // uchar[3 MB] fp8 fragment-major
#define WS_POS_OFF  (TOT * 256)                  // float[4096*2] pos distances
#define WS_PART_OFF (WS_POS_OFF + NB * NP * 4)   // float[3][4096][16] partial maxima

// Kernel 1: normalize rows of [a | p0 | p1] -> fp8 e4m3, written in
// fragment-major layout; p-rows also emit the exact fp32 positive distance.
__global__ void norm_pos_kernel(const float* __restrict__ anchor,
                                const float* __restrict__ positive,
                                unsigned char* __restrict__ F2,
                                float* __restrict__ posArr) {
    int wid = threadIdx.x >> 6, lane = threadIdx.x & 63;
    int row = blockIdx.x * 4 + wid;              // grid = 3072
    // fragment-major destination for this lane's 4 bytes (k = lane*4):
    int group = row >> 4, r15 = row & 15;
    int kk = lane >> 3, quad = (lane >> 1) & 3, jj = (lane & 1) * 4;
    int* dst = (int*)(F2 + (size_t)group * 4096 + kk * 512 + (quad * 16 + r15) * 8 + jj);

    if (row < NB) {
        const float* src = anchor + (size_t)row * ND;
        float4 x = *(const float4*)(src + lane * 4);
        float ss = x.x * x.x + x.y * x.y + x.z * x.z + x.w * x.w;
        #pragma unroll
        for (int m = 1; m < 64; m <<= 1) ss += __shfl_xor(ss, m, 64);
        float inv = 1.0f / fmaxf(sqrtf(ss), 1e-12f);
        int pk = __builtin_amdgcn_cvt_pk_fp8_f32(x.x * inv, x.y * inv, 0, false);
        pk = __builtin_amdgcn_cvt_pk_fp8_f32(x.z * inv, x.w * inv, pk, true);
        *dst = pk;
    } else {
        int q = row - NB;
        int v = q >> 12;                         // 0 or 1
        int j = q & (NB - 1);
        const float* sp = positive + (size_t)(j * NP + v) * ND;
        const float* sa = anchor + (size_t)j * ND;
        float4 xp = *(const float4*)(sp + lane * 4);
        float4 xa = *(const float4*)(sa + lane * 4);
        float sspv = xp.x * xp.x + xp.y * xp.y + xp.z * xp.z + xp.w * xp.w;
        float ssa  = xa.x * xa.x + xa.y * xa.y + xa.z * xa.z + xa.w * xa.w;
        float dot  = xa.x * xp.x + xa.y * xp.y + xa.z * xp.z + xa.w * xp.w;
        #pragma unroll
        for (int m = 1; m < 64; m <<= 1) {
            sspv += __shfl_xor(sspv, m, 64);
            ssa  += __shfl_xor(ssa, m, 64);
            dot  += __shfl_xor(dot, m, 64);
        }
        float invp = 1.0f / fmaxf(sqrtf(sspv), 1e-12f);
        int pk = __builtin_amdgcn_cvt_pk_fp8_f32(xp.x * invp, xp.y * invp, 0, false);
        pk = __builtin_amdgcn_cvt_pk_fp8_f32(xp.z * invp, xp.w * invp, pk, true);
        *dst = pk;
        if (lane == 0) {
            float inva = 1.0f / fmaxf(sqrtf(ssa), 1e-12f);
            float dn = dot * inva * invp;
            float sq = 2.0f - 2.0f * dn;
            posArr[j * NP + v] = sqrtf(fmaxf(sq, 1e-12f));
        }
    }
}

// Kernel 2: fused masked-max Gram, FP8, fragment-major F2, barrier-free
// K-loop (R9 structure). A-preload: 32 coalesced 512-B wave loads. B-staging:
// flat 64 KB memcpy (already in fragment layout). F2 = 3 MB fits per-XCD L2.
__global__ __launch_bounds__(256) void gram_max_kernel(
        const unsigned char* __restrict__ F2,
        const int* __restrict__ labels,
        float* __restrict__ partials) {
    __shared__ unsigned char ldsB[TILES * 4096];  // 64 KB
    __shared__ int slab[COLS_PER_CHUNK];          // 1 KB column labels
    int tid = threadIdx.x;
    int wid = tid >> 6, lane = tid & 63;
    int l15 = lane & 15, quad = lane >> 4;

    int id = blockIdx.x;                         // 0..767
    int chunk = id >> 4;                         // 0..47
    int rbi   = id & 15;                         // 0..15 row-block index

    int rowBase = rbi * 256 + wid * 64;
    int col0 = chunk * COLS_PER_CHUNK;
    int part = chunk >> 4;                       // 0=aa, 1=p0, 2=p1

    slab[tid] = labels[(col0 & (NB - 1)) + tid];

    // ---- B staging: straight 64 KB copy, 16 B/lane coalesced, layout
    //      identical to what the K-loop reads.
    {
        const float4* src = (const float4*)(F2 + (size_t)chunk * 16 * 4096);
        float4* dst = (float4*)ldsB;
        #pragma unroll
        for (int j = 0; j < 16; ++j)
            dst[tid + j * 256] = src[tid + j * 256];
    }

    // ---- A preload: af[s][kk] from fragment-major group rbi*16+wid*4+s.
    long af[4][8];
    #pragma unroll
    for (int s = 0; s < 4; ++s) {
        const unsigned char* ab = F2 + (size_t)(rbi * 16 + wid * 4 + s) * 4096 + lane * 8;
        #pragma unroll
        for (int kk = 0; kk < 8; ++kk)
            af[s][kk] = *(const long*)(ab + kk * 512);
    }
    // Row labels, byte-packed (labels < 200 fit a byte). C row = quad*4+r.
    unsigned rlp[4];
    #pragma unroll
    for (int s = 0; s < 4; ++s) {
        const int* lb = labels + rowBase + s * 16 + quad * 4;
        rlp[s] = (unsigned)lb[0] | ((unsigned)lb[1] << 8)
               | ((unsigned)lb[2] << 16) | ((unsigned)lb[3] << 24);
    }

    float vmax[4][4];
    #pragma unroll
    for (int s = 0; s < 4; ++s)
        #pragma unroll
        for (int r = 0; r < 4; ++r) vmax[s][r] = NEG_INIT;

    __syncthreads();   // the ONLY barrier

    // ---- Barrier-free K-loop: pure ds_read + MFMA + mask-fold.
    #pragma unroll 2
    for (int ct = 0; ct < TILES; ++ct) {
        long bfr[8];
        #pragma unroll
        for (int kk = 0; kk < 8; ++kk)
            bfr[kk] = *(const long*)&ldsB[ct * 4096 + kk * 512 + lane * 8];

        int lc = slab[ct * 16 + l15];
        unsigned lcq = (unsigned)lc * 0x01010101u;

        f32x4 acc[4];
        #pragma unroll
        for (int s = 0; s < 4; ++s) acc[s] = (f32x4){0.f, 0.f, 0.f, 0.f};
        #pragma unroll
        for (int kk = 0; kk < 8; ++kk)
            #pragma unroll
            for (int s = 0; s < 4; ++s)
                acc[s] = __builtin_amdgcn_mfma_f32_16x16x32_fp8_fp8(af[s][kk], bfr[kk], acc[s], 0, 0, 0);

        #pragma unroll
        for (int s = 0; s < 4; ++s) {
            unsigned x = rlp[s] ^ lcq;         // byte r == 0 iff labels equal
            #pragma unroll
            for (int r = 0; r < 4; ++r) {
                bool neq = ((x >> (8 * r)) & 0xffu) != 0u;
                vmax[s][r] = fmaxf(vmax[s][r], neq ? acc[s][r] : NEG_INIT);
            }
        }
    }

    // Reduce max across the 16 column-lanes (same quad = same rows)
    #pragma unroll
    for (int m = 1; m < 16; m <<= 1)
        #pragma unroll
        for (int s = 0; s < 4; ++s)
            #pragma unroll
            for (int r = 0; r < 4; ++r)
                vmax[s][r] = fmaxf(vmax[s][r], __shfl_xor(vmax[s][r], m, 64));

    if (l15 == 0) {
        #pragma unroll
        for (int s = 0; s < 4; ++s)
            #pragma unroll
            for (int r = 0; r < 4; ++r) {
                int row = rowBase + s * 16 + quad * 4 + r;
                partials[(size_t)part * NB * 16 + (size_t)row * 16 + (chunk & 15)] = vmax[s][r];
            }
    }
}

// Kernel 3: combine per-part chunk partials -> neg distances -> hinge -> mean.
__global__ void finalize_kernel(const float* __restrict__ partials,
                                const float* __restrict__ posArr,
                                float* __restrict__ out) {
    int row = blockIdx.x * 256 + threadIdx.x;    // grid = 16 -> 4096 rows
    const float* pa = partials + (size_t)row * 16;
    const float* pb = pa + (size_t)NB * 16;
    const float* pc = pb + (size_t)NB * 16;
    float ma = NEG_INIT, m0 = NEG_INIT, m1 = NEG_INIT;
    #pragma unroll
    for (int j = 0; j < 16; ++j) {
        ma = fmaxf(ma, pa[j]);
        m0 = fmaxf(m0, pb[j]);
        m1 = fmaxf(m1, pc[j]);
    }
    float n0 = sqrtf(fmaxf(2.0f - 2.0f * fmaxf(ma, m0), 1e-12f));
    float n1 = sqrtf(fmaxf(2.0f - 2.0f * fmaxf(ma, m1), 1e-12f));
    float l = fmaxf(posArr[row * 2 + 0] - n0 + 1.0f, 0.0f)
            + fmaxf(posArr[row * 2 + 1] - n1 + 1.0f, 0.0f);
    int lane = threadIdx.x & 63, wid = threadIdx.x >> 6;
    #pragma unroll
    for (int m = 1; m < 64; m <<= 1) l += __shfl_xor(l, m, 64);
    __shared__ float wsum[4];
    if (lane == 0) wsum[wid] = l;
    __syncthreads();
    if (threadIdx.x == 0) {
        float s = wsum[0] + wsum[1] + wsum[2] + wsum[3];
        atomicAdd(out, s * (1.0f / (NB * NP)));
    }
}

extern "C" void kernel_launch(void* const* d_in, const int* in_sizes, int n_in,
                              void* d_out, int out_size, void* d_ws, size_t ws_size,
                              hipStream_t stream) {
    const float* anchor   = (const float*)d_in[0];
    const float* positive = (const float*)d_in[1];
    const int*   labels   = (const int*)d_in[2];
    float* out = (float*)d_out;

    unsigned char* F2 = (unsigned char*)((char*)d_ws + WS_F_OFF);
    float* posArr     = (float*)((char*)d_ws + WS_POS_OFF);
    float* partials   = (float*)((char*)d_ws + WS_PART_OFF);

    norm_pos_kernel<<<TOT / 4, 256, 0, stream>>>(anchor, positive, F2, posArr);
    gram_max_kernel<<<(NB / 256) * NCHUNK, 256, 0, stream>>>(F2, labels, partials);
    hipMemsetAsync(d_out, 0, sizeof(float), stream);
    finalize_kernel<<<NB / 256, 256, 0, stream>>>(partials, posArr, out);
}

// Round 12
// 89.611 us; speedup vs baseline: 1.2631x; 1.0441x over previous
//
#include <hip/hip_runtime.h>
#include <hip/hip_bf16.h>

// Problem constants
#define NB    4096          // batch
#define ND    256           // dim
#define NP    2             // positives per anchor
#define TOT   (NB * 3)      // 12288 rows: [a | p0 | p1]
#define NCHUNK 48           // 3 parts x 16 chunks; each chunk within one part
#define COLS_PER_CHUNK 256
#define TILES 16
#define NEG_INIT (-4.0f)

// F2 is FRAGMENT-MAJOR (see R11): for 16-row group g, K-block kk, the 512-B
// block F2[g*4096 + kk*512 + (quad*16 + r15)*8 + j] holds K-byte
// kk*32 + quad*8 + j of row g*16 + r15. MFMA fragment loads are lane*8
// contiguous (512 B/wave, 8 cache lines).
typedef float f32x4 __attribute__((ext_vector_type(4)));

// ws layout (bytes)
#define WS_F_OFF    0                            // uchar[3 MB] fp8 fragment-major
#define WS_POS_OFF  (TOT * 256)                  // float[4096*2] pos distances
#define WS_PART_OFF (WS_POS_OFF + NB * NP * 4)   // float[3][4096][16] partial maxima

// Kernel 1: normalize rows of [a | p0 | p1] -> fp8 e4m3, fragment-major;
// p-rows also emit the exact fp32 positive distance. One wave per row.
__global__ void norm_pos_kernel(const float* __restrict__ anchor,
                                const float* __restrict__ positive,
                                unsigned char* __restrict__ F2,
                                float* __restrict__ posArr) {
    int wid = threadIdx.x >> 6, lane = threadIdx.x & 63;
    int row = blockIdx.x * 4 + wid;              // grid = 3072
    int group = row >> 4, r15 = row & 15;
    int kk = lane >> 3, quad = (lane >> 1) & 3, jj = (lane & 1) * 4;
    int* dst = (int*)(F2 + (size_t)group * 4096 + kk * 512 + (quad * 16 + r15) * 8 + jj);

    if (row < NB) {
        const float* src = anchor + (size_t)row * ND;
        float4 x = *(const float4*)(src + lane * 4);
        float ss = x.x * x.x + x.y * x.y + x.z * x.z + x.w * x.w;
        #pragma unroll
        for (int m = 1; m < 64; m <<= 1) ss += __shfl_xor(ss, m, 64);
        float inv = 1.0f / fmaxf(sqrtf(ss), 1e-12f);
        int pk = __builtin_amdgcn_cvt_pk_fp8_f32(x.x * inv, x.y * inv, 0, false);
        pk = __builtin_amdgcn_cvt_pk_fp8_f32(x.z * inv, x.w * inv, pk, true);
        *dst = pk;
    } else {
        int q = row - NB;
        int v = q >> 12;                         // 0 or 1
        int j = q & (NB - 1);
        const float* sp = positive + (size_t)(j * NP + v) * ND;
        const float* sa = anchor + (size_t)j * ND;
        float4 xp = *(const float4*)(sp + lane * 4);
        float4 xa = *(const float4*)(sa + lane * 4);
        float sspv = xp.x * xp.x + xp.y * xp.y + xp.z * xp.z + xp.w * xp.w;
        float ssa  = xa.x * xa.x + xa.y * xa.y + xa.z * xa.z + xa.w * xa.w;
        float dot  = xa.x * xp.x + xa.y * xp.y + xa.z * xp.z + xa.w * xp.w;
        #pragma unroll
        for (int m = 1; m < 64; m <<= 1) {
            sspv += __shfl_xor(sspv, m, 64);
            ssa  += __shfl_xor(ssa, m, 64);
            dot  += __shfl_xor(dot, m, 64);
        }
        float invp = 1.0f / fmaxf(sqrtf(sspv), 1e-12f);
        int pk = __builtin_amdgcn_cvt_pk_fp8_f32(xp.x * invp, xp.y * invp, 0, false);
        pk = __builtin_amdgcn_cvt_pk_fp8_f32(xp.z * invp, xp.w * invp, pk, true);
        *dst = pk;
        if (lane == 0) {
            float inva = 1.0f / fmaxf(sqrtf(ssa), 1e-12f);
            float dn = dot * inva * invp;
            float sq = 2.0f - 2.0f * dn;
            posArr[j * NP + v] = sqrtf(fmaxf(sq, 1e-12f));
        }
    }
}

// Kernel 2: fused masked-max Gram, FP8, fragment-major, barrier-free K-loop.
// 512-thread blocks (8 waves x 32 rows): 2 blocks/CU (64 KB LDS) now give
// 16 waves/CU instead of 8 -- doubles TLP at identical global traffic.
// VGPR ~110 (af halved to 2 groups) -> 4 waves/SIMD fits.
__global__ __launch_bounds__(512) void gram_max_kernel(
        const unsigned char* __restrict__ F2,
        const int* __restrict__ labels,
        float* __restrict__ partials) {
    __shared__ unsigned char ldsB[TILES * 4096];  // 64 KB
    __shared__ int slab[COLS_PER_CHUNK];          // 1 KB column labels
    int tid = threadIdx.x;
    int wid = tid >> 6, lane = tid & 63;
    int l15 = lane & 15, quad = lane >> 4;

    int id = blockIdx.x;                         // 0..767
    int chunk = id >> 4;                         // 0..47
    int rbi   = id & 15;                         // 0..15 row-block index

    int rowBase = rbi * 256 + wid * 32;          // 32 rows per wave
    int col0 = chunk * COLS_PER_CHUNK;
    int part = chunk >> 4;                       // 0=aa, 1=p0, 2=p1

    // ---- A preload first (global latency overlaps B staging below):
    // af[s][kk] from fragment-major group rbi*16 + wid*2 + s.
    long af[2][8];
    #pragma unroll
    for (int s = 0; s < 2; ++s) {
        const unsigned char* ab = F2 + (size_t)(rbi * 16 + wid * 2 + s) * 4096 + lane * 8;
        #pragma unroll
        for (int kk = 0; kk < 8; ++kk)
            af[s][kk] = *(const long*)(ab + kk * 512);
    }
    // Row labels, byte-packed (labels < 200 fit a byte). C row = quad*4+r.
    unsigned rlp[2];
    #pragma unroll
    for (int s = 0; s < 2; ++s) {
        const int* lb = labels + rowBase + s * 16 + quad * 4;
        rlp[s] = (unsigned)lb[0] | ((unsigned)lb[1] << 8)
               | ((unsigned)lb[2] << 16) | ((unsigned)lb[3] << 24);
    }
    if (tid < COLS_PER_CHUNK) slab[tid] = labels[(col0 & (NB - 1)) + tid];

    // ---- B staging: flat 64 KB copy, 16 B/thread x 8, already in fragment
    //      layout.
    {
        const float4* src = (const float4*)(F2 + (size_t)chunk * 16 * 4096);
        float4* dst = (float4*)ldsB;
        #pragma unroll
        for (int j = 0; j < 8; ++j)
            dst[tid + j * 512] = src[tid + j * 512];
    }

    float vmax[2][4];
    #pragma unroll
    for (int s = 0; s < 2; ++s)
        #pragma unroll
        for (int r = 0; r < 4; ++r) vmax[s][r] = NEG_INIT;

    __syncthreads();   // the ONLY barrier

    // ---- Barrier-free K-loop: pure ds_read + MFMA + mask-fold.
    #pragma unroll 2
    for (int ct = 0; ct < TILES; ++ct) {
        long bfr[8];
        #pragma unroll
        for (int kk = 0; kk < 8; ++kk)
            bfr[kk] = *(const long*)&ldsB[ct * 4096 + kk * 512 + lane * 8];

        int lc = slab[ct * 16 + l15];
        unsigned lcq = (unsigned)lc * 0x01010101u;

        f32x4 acc[2];
        #pragma unroll
        for (int s = 0; s < 2; ++s) acc[s] = (f32x4){0.f, 0.f, 0.f, 0.f};
        #pragma unroll
        for (int kk = 0; kk < 8; ++kk)
            #pragma unroll
            for (int s = 0; s < 2; ++s)
                acc[s] = __builtin_amdgcn_mfma_f32_16x16x32_fp8_fp8(af[s][kk], bfr[kk], acc[s], 0, 0, 0);

        #pragma unroll
        for (int s = 0; s < 2; ++s) {
            unsigned x = rlp[s] ^ lcq;         // byte r == 0 iff labels equal
            #pragma unroll
            for (int r = 0; r < 4; ++r) {
                bool neq = ((x >> (8 * r)) & 0xffu) != 0u;
                vmax[s][r] = fmaxf(vmax[s][r], neq ? acc[s][r] : NEG_INIT);
            }
        }
    }

    // Reduce max across the 16 column-lanes (same quad = same rows)
    #pragma unroll
    for (int m = 1; m < 16; m <<= 1)
        #pragma unroll
        for (int s = 0; s < 2; ++s)
            #pragma unroll
            for (int r = 0; r < 4; ++r)
                vmax[s][r] = fmaxf(vmax[s][r], __shfl_xor(vmax[s][r], m, 64));

    if (l15 == 0) {
        #pragma unroll
        for (int s = 0; s < 2; ++s)
            #pragma unroll
            for (int r = 0; r < 4; ++r) {
                int row = rowBase + s * 16 + quad * 4 + r;
                partials[(size_t)part * NB * 16 + (size_t)row * 16 + (chunk & 15)] = vmax[s][r];
            }
    }
}

// Kernel 3: combine per-part chunk partials -> neg distances -> hinge -> mean.
__global__ void finalize_kernel(const float* __restrict__ partials,
                                const float* __restrict__ posArr,
                                float* __restrict__ out) {
    int row = blockIdx.x * 256 + threadIdx.x;    // grid = 16 -> 4096 rows
    const float* pa = partials + (size_t)row * 16;
    const float* pb = pa + (size_t)NB * 16;
    const float* pc = pb + (size_t)NB * 16;
    float ma = NEG_INIT, m0 = NEG_INIT, m1 = NEG_INIT;
    #pragma unroll
    for (int j = 0; j < 16; ++j) {
        ma = fmaxf(ma, pa[j]);
        m0 = fmaxf(m0, pb[j]);
        m1 = fmaxf(m1, pc[j]);
    }
    float n0 = sqrtf(fmaxf(2.0f - 2.0f * fmaxf(ma, m0), 1e-12f));
    float n1 = sqrtf(fmaxf(2.0f - 2.0f * fmaxf(ma, m1), 1e-12f));
    float l = fmaxf(posArr[row * 2 + 0] - n0 + 1.0f, 0.0f)
            + fmaxf(posArr[row * 2 + 1] - n1 + 1.0f, 0.0f);
    int lane = threadIdx.x & 63, wid = threadIdx.x >> 6;
    #pragma unroll
    for (int m = 1; m < 64; m <<= 1) l += __shfl_xor(l, m, 64);
    __shared__ float wsum[4];
    if (lane == 0) wsum[wid] = l;
    __syncthreads();
    if (threadIdx.x == 0) {
        float s = wsum[0] + wsum[1] + wsum[2] + wsum[3];
        atomicAdd(out, s * (1.0f / (NB * NP)));
    }
}

extern "C" void kernel_launch(void* const* d_in, const int* in_sizes, int n_in,
                              void* d_out, int out_size, void* d_ws, size_t ws_size,
                              hipStream_t stream) {
    const float* anchor   = (const float*)d_in[0];
    const float* positive = (const float*)d_in[1];
    const int*   labels   = (const int*)d_in[2];
    float* out = (float*)d_out;

    unsigned char* F2 = (unsigned char*)((char*)d_ws + WS_F_OFF);
    float* posArr     = (float*)((char*)d_ws + WS_POS_OFF);
    float* partials   = (float*)((char*)d_ws + WS_PART_OFF);

    norm_pos_kernel<<<TOT / 4, 256, 0, stream>>>(anchor, positive, F2, posArr);
    gram_max_kernel<<<(NB / 256) * NCHUNK, 512, 0, stream>>>(F2, labels, partials);
    hipMemsetAsync(d_out, 0, sizeof(float), stream);
    finalize_kernel<<<NB / 256, 256, 0, stream>>>(partials, posArr, out);
}

// Round 13
// 86.766 us; speedup vs baseline: 1.3045x; 1.0328x over previous
//
#include <hip/hip_runtime.h>
#include <hip/hip_bf16.h>

// Problem constants
#define NB    4096          // batch
#define ND    256           // dim
#define NP    2             // positives per anchor
#define TOT   (NB * 3)      // 12288 rows: [a | p0 | p1]
#define NCHUNK 48           // 3 parts x 16 chunks; each chunk within one part
#define COLS_PER_CHUNK 256
#define TILES 16
#define NEG_INIT (-4.0f)
#define IMIN_SENT (-1073741824)   // mask sentinel for int dots
#define INV_SCALE (1.0f / 16129.0f)  // 1/(127*127)

// F2 is FRAGMENT-MAJOR i8: for 16-row group g, K-block kk (64 i8), the 1024-B
// block F2[g*4096 + kk*1024 + (quad*16 + r15)*16 + j] holds K-byte
// kk*64 + quad*16 + j of row g*16 + r15. MFMA fragment loads are lane*16
// contiguous (1 KB/wave b128 loads). Same bytes-per-lane convention verified
// by the fp8 path (R8) and the guide's bf16 mapping.
typedef float f32x4 __attribute__((ext_vector_type(4)));
typedef int   i32x4 __attribute__((ext_vector_type(4)));

// ws layout (bytes)
#define WS_F_OFF    0                            // uchar[3 MB] i8 fragment-major
#define WS_POS_OFF  (TOT * 256)                  // float[4096*2] pos distances
#define WS_PART_OFF (WS_POS_OFF + NB * NP * 4)   // float[3][4096][16] partial maxima

// Kernel 1: normalize rows of [a | p0 | p1] -> i8 (x127), fragment-major;
// p-rows also emit the exact fp32 positive distance. One wave per row.
__global__ void norm_pos_kernel(const float* __restrict__ anchor,
                                const float* __restrict__ positive,
                                unsigned char* __restrict__ F2,
                                float* __restrict__ posArr) {
    int wid = threadIdx.x >> 6, lane = threadIdx.x & 63;
    int row = blockIdx.x * 4 + wid;              // grid = 3072
    int group = row >> 4, r15 = row & 15;
    int kk = lane >> 4, quad = (lane >> 2) & 3, jj = (lane & 3) * 4;
    int* dst = (int*)(F2 + (size_t)group * 4096 + kk * 1024 + (quad * 16 + r15) * 16 + jj);

    if (row < NB) {
        const float* src = anchor + (size_t)row * ND;
        float4 x = *(const float4*)(src + lane * 4);
        float ss = x.x * x.x + x.y * x.y + x.z * x.z + x.w * x.w;
        #pragma unroll
        for (int m = 1; m < 64; m <<= 1) ss += __shfl_xor(ss, m, 64);
        float inv = 127.0f / fmaxf(sqrtf(ss), 1e-12f);
        int b0 = (int)rintf(x.x * inv) & 0xff;
        int b1 = (int)rintf(x.y * inv) & 0xff;
        int b2 = (int)rintf(x.z * inv) & 0xff;
        int b3 = (int)rintf(x.w * inv) & 0xff;
        *dst = b0 | (b1 << 8) | (b2 << 16) | (b3 << 24);
    } else {
        int q = row - NB;
        int v = q >> 12;                         // 0 or 1
        int j = q & (NB - 1);
        const float* sp = positive + (size_t)(j * NP + v) * ND;
        const float* sa = anchor + (size_t)j * ND;
        float4 xp = *(const float4*)(sp + lane * 4);
        float4 xa = *(const float4*)(sa + lane * 4);
        float sspv = xp.x * xp.x + xp.y * xp.y + xp.z * xp.z + xp.w * xp.w;
        float ssa  = xa.x * xa.x + xa.y * xa.y + xa.z * xa.z + xa.w * xa.w;
        float dot  = xa.x * xp.x + xa.y * xp.y + xa.z * xp.z + xa.w * xp.w;
        #pragma unroll
        for (int m = 1; m < 64; m <<= 1) {
            sspv += __shfl_xor(sspv, m, 64);
            ssa  += __shfl_xor(ssa, m, 64);
            dot  += __shfl_xor(dot, m, 64);
        }
        float invp = 127.0f / fmaxf(sqrtf(sspv), 1e-12f);
        int b0 = (int)rintf(xp.x * invp) & 0xff;
        int b1 = (int)rintf(xp.y * invp) & 0xff;
        int b2 = (int)rintf(xp.z * invp) & 0xff;
        int b3 = (int)rintf(xp.w * invp) & 0xff;
        *dst = b0 | (b1 << 8) | (b2 << 16) | (b3 << 24);
        if (lane == 0) {
            float inva = 1.0f / fmaxf(sqrtf(ssa), 1e-12f);
            float invpf = invp * (1.0f / 127.0f);
            float dn = dot * inva * invpf;
            float sq = 2.0f - 2.0f * dn;
            posArr[j * NP + v] = sqrtf(fmaxf(sq, 1e-12f));
        }
    }
}

// Kernel 2: fused masked-max Gram, INT8 (2x MFMA rate vs fp8/bf16),
// fragment-major, barrier-free K-loop, 512-thread blocks (R12 structure).
// Int32 dots are exact; max over ints is order-exact. Partials stored as
// float(acc)/127^2.
__global__ __launch_bounds__(512) void gram_max_kernel(
        const unsigned char* __restrict__ F2,
        const int* __restrict__ labels,
        float* __restrict__ partials) {
    __shared__ unsigned char ldsB[TILES * 4096];  // 64 KB
    __shared__ int slab[COLS_PER_CHUNK];          // 1 KB column labels
    int tid = threadIdx.x;
    int wid = tid >> 6, lane = tid & 63;
    int l15 = lane & 15, quad = lane >> 4;

    int id = blockIdx.x;                         // 0..767
    int chunk = id >> 4;                         // 0..47
    int rbi   = id & 15;                         // 0..15 row-block index

    int rowBase = rbi * 256 + wid * 32;          // 32 rows per wave
    int col0 = chunk * COLS_PER_CHUNK;
    int part = chunk >> 4;                       // 0=aa, 1=p0, 2=p1

    // ---- A preload (b128, 1 KB/wave-load): groups rbi*16 + wid*2 + s.
    i32x4 af[2][4];
    #pragma unroll
    for (int s = 0; s < 2; ++s) {
        const unsigned char* ab = F2 + (size_t)(rbi * 16 + wid * 2 + s) * 4096 + lane * 16;
        #pragma unroll
        for (int kk = 0; kk < 4; ++kk)
            af[s][kk] = *(const i32x4*)(ab + kk * 1024);
    }
    // Row labels, byte-packed (labels < 200 fit a byte). C row = quad*4+r.
    unsigned rlp[2];
    #pragma unroll
    for (int s = 0; s < 2; ++s) {
        const int* lb = labels + rowBase + s * 16 + quad * 4;
        rlp[s] = (unsigned)lb[0] | ((unsigned)lb[1] << 8)
               | ((unsigned)lb[2] << 16) | ((unsigned)lb[3] << 24);
    }
    if (tid < COLS_PER_CHUNK) slab[tid] = labels[(col0 & (NB - 1)) + tid];

    // ---- B staging: flat 64 KB copy, already in fragment layout.
    {
        const float4* src = (const float4*)(F2 + (size_t)chunk * 16 * 4096);
        float4* dst = (float4*)ldsB;
        #pragma unroll
        for (int j = 0; j < 8; ++j)
            dst[tid + j * 512] = src[tid + j * 512];
    }

    int vmax[2][4];
    #pragma unroll
    for (int s = 0; s < 2; ++s)
        #pragma unroll
        for (int r = 0; r < 4; ++r) vmax[s][r] = IMIN_SENT;

    __syncthreads();   // the ONLY barrier

    // ---- Barrier-free K-loop: 4 b128 ds_reads + 8 MFMA + mask-fold per tile.
    #pragma unroll 2
    for (int ct = 0; ct < TILES; ++ct) {
        i32x4 bfr[4];
        #pragma unroll
        for (int kk = 0; kk < 4; ++kk)
            bfr[kk] = *(const i32x4*)&ldsB[ct * 4096 + kk * 1024 + lane * 16];

        int lc = slab[ct * 16 + l15];
        unsigned lcq = (unsigned)lc * 0x01010101u;

        i32x4 acc[2];
        #pragma unroll
        for (int s = 0; s < 2; ++s) acc[s] = (i32x4){0, 0, 0, 0};
        #pragma unroll
        for (int kk = 0; kk < 4; ++kk)
            #pragma unroll
            for (int s = 0; s < 2; ++s)
                acc[s] = __builtin_amdgcn_mfma_i32_16x16x64_i8(af[s][kk], bfr[kk], acc[s], 0, 0, 0);

        #pragma unroll
        for (int s = 0; s < 2; ++s) {
            unsigned x = rlp[s] ^ lcq;         // byte r == 0 iff labels equal
            #pragma unroll
            for (int r = 0; r < 4; ++r) {
                bool neq = ((x >> (8 * r)) & 0xffu) != 0u;
                int cand = neq ? acc[s][r] : IMIN_SENT;
                vmax[s][r] = vmax[s][r] > cand ? vmax[s][r] : cand;
            }
        }
    }

    // Reduce max across the 16 column-lanes (same quad = same rows)
    #pragma unroll
    for (int m = 1; m < 16; m <<= 1)
        #pragma unroll
        for (int s = 0; s < 2; ++s)
            #pragma unroll
            for (int r = 0; r < 4; ++r) {
                int o = __shfl_xor(vmax[s][r], m, 64);
                vmax[s][r] = vmax[s][r] > o ? vmax[s][r] : o;
            }

    if (l15 == 0) {
        #pragma unroll
        for (int s = 0; s < 2; ++s)
            #pragma unroll
            for (int r = 0; r < 4; ++r) {
                int row = rowBase + s * 16 + quad * 4 + r;
                partials[(size_t)part * NB * 16 + (size_t)row * 16 + (chunk & 15)]
                    = (float)vmax[s][r] * INV_SCALE;
            }
    }
}

// Kernel 3: combine per-part chunk partials -> neg distances -> hinge -> mean.
__global__ void finalize_kernel(const float* __restrict__ partials,
                                const float* __restrict__ posArr,
                                float* __restrict__ out) {
    int row = blockIdx.x * 256 + threadIdx.x;    // grid = 16 -> 4096 rows
    const float* pa = partials + (size_t)row * 16;
    const float* pb = pa + (size_t)NB * 16;
    const float* pc = pb + (size_t)NB * 16;
    float ma = NEG_INIT, m0 = NEG_INIT, m1 = NEG_INIT;
    #pragma unroll
    for (int j = 0; j < 16; ++j) {
        ma = fmaxf(ma, pa[j]);
        m0 = fmaxf(m0, pb[j]);
        m1 = fmaxf(m1, pc[j]);
    }
    float n0 = sqrtf(fmaxf(2.0f - 2.0f * fmaxf(ma, m0), 1e-12f));
    float n1 = sqrtf(fmaxf(2.0f - 2.0f * fmaxf(ma, m1), 1e-12f));
    float l = fmaxf(posArr[row * 2 + 0] - n0 + 1.0f, 0.0f)
            + fmaxf(posArr[row * 2 + 1] - n1 + 1.0f, 0.0f);
    int lane = threadIdx.x & 63, wid = threadIdx.x >> 6;
    #pragma unroll
    for (int m = 1; m < 64; m <<= 1) l += __shfl_xor(l, m, 64);
    __shared__ float wsum[4];
    if (lane == 0) wsum[wid] = l;
    __syncthreads();
    if (threadIdx.x == 0) {
        float s = wsum[0] + wsum[1] + wsum[2] + wsum[3];
        atomicAdd(out, s * (1.0f / (NB * NP)));
    }
}

extern "C" void kernel_launch(void* const* d_in, const int* in_sizes, int n_in,
                              void* d_out, int out_size, void* d_ws, size_t ws_size,
                              hipStream_t stream) {
    const float* anchor   = (const float*)d_in[0];
    const float* positive = (const float*)d_in[1];
    const int*   labels   = (const int*)d_in[2];
    float* out = (float*)d_out;

    unsigned char* F2 = (unsigned char*)((char*)d_ws + WS_F_OFF);
    float* posArr     = (float*)((char*)d_ws + WS_POS_OFF);
    float* partials   = (float*)((char*)d_ws + WS_PART_OFF);

    norm_pos_kernel<<<TOT / 4, 256, 0, stream>>>(anchor, positive, F2, posArr);
    gram_max_kernel<<<(NB / 256) * NCHUNK, 512, 0, stream>>>(F2, labels, partials);
    hipMemsetAsync(d_out, 0, sizeof(float), stream);
    finalize_kernel<<<NB / 256, 256, 0, stream>>>(partials, posArr, out);
}